// Round 17
// baseline (234.470 us; speedup 1.0000x reference)
//
#include <hip/hip_runtime.h>
#include <hip/hip_fp16.h>

typedef __attribute__((ext_vector_type(4))) float f32x4;
typedef __attribute__((ext_vector_type(4))) int i32x4;
typedef _Float16 f16x8 __attribute__((ext_vector_type(8)));
typedef _Float16 f16x4 __attribute__((ext_vector_type(4)));

#define EPB 4096      // edges per partition block
#define NBKT 196      // ceil(100000/512) buckets of 512 nodes
#define BCAP 10240    // arena capacity per bucket (mean 8192, +22 sigma)

// =============== init: zero bktCur + pooled, prepack W4 (replaces 2 memsets+1k) ==
// W4 B-fragment: elem i of lane l holds B[k][n], n = ct*16+(l&15),
// k = kk*32 + 4*(l>>4) + (i&3) + 16*(i>>2)   [m156/m162-derived, R16-verified]
__global__ __launch_bounds__(256)
void init_kernel(int* __restrict__ bktCur, float* __restrict__ pooled,
                 const float* __restrict__ W, _Float16* __restrict__ Wpk) {
    const int gid = blockIdx.x * 256 + threadIdx.x;
    if (gid < NBKT) bktCur[gid] = 0;
    if (gid < 512 * 128) pooled[gid] = 0.f;
    if (gid < 8192) {
        const int i = gid & 7;
        const int l = (gid >> 3) & 63;
        const int kk = (gid >> 9) & 1;
        const int ct = gid >> 10;
        const int k = kk * 32 + 4 * (l >> 4) + (i & 3) + 16 * (i >> 2);
        const int col = ct * 16 + (l & 15);
        Wpk[gid] = (_Float16)W[k * 128 + col];
    }
}

// =============== Phase B: partition edges into per-bucket arenas ================
__global__ __launch_bounds__(256)
void partition_kernel(const int* __restrict__ ei, int E,
                      int* __restrict__ bktCur, int* __restrict__ arena) {
    __shared__ int sHist[256];
    __shared__ int sScan[256];
    __shared__ int sAdj[256];
    __shared__ int2 sEdges[EPB];     // 32 KB staging
    const int t = threadIdx.x;
    const int e0 = blockIdx.x * EPB;
    const int ecnt = min(EPB, E - e0);
    const int* src = ei;
    const int* dst = ei + E;

    sHist[t] = 0;
    __syncthreads();
    for (int k = t; k < ecnt; k += 256) {
        const int s = src[e0 + k], d = dst[e0 + k];
        sEdges[k] = make_int2(s, d);
        atomicAdd(&sHist[d >> 9], 1);
    }
    __syncthreads();
    const int v = sHist[t];
    sScan[t] = v;
    __syncthreads();
    #pragma unroll
    for (int off = 1; off < 256; off <<= 1) {
        const int y = (t >= off) ? sScan[t - off] : 0;
        __syncthreads();
        sScan[t] += y;
        __syncthreads();
    }
    const int excl = sScan[t] - v;
    if (t < NBKT && v > 0) {
        const int g = atomicAdd(&bktCur[t], v);
        sAdj[t] = t * BCAP + g - excl;
    }
    sHist[t] = excl;
    __syncthreads();
    for (int k = t; k < ecnt; k += 256) {
        const int2 e = sEdges[k];
        const int b = e.y >> 9;
        const int p = atomicAdd(&sHist[b], 1);
        arena[sAdj[b] + p] = (e.x << 9) | (e.y & 511);
    }
}

// =============== Phase C: per-bucket CSR build + meta + dis + g0 = dis*x =========
__global__ __launch_bounds__(512)
void bucket_csr_kernel(const int* __restrict__ arena, const int* __restrict__ bktCur,
                       int* __restrict__ csr_src, int2* __restrict__ meta,
                       float* __restrict__ dis, const float* __restrict__ x,
                       float* __restrict__ g0, int n) {
    __shared__ int sHist[512];
    __shared__ int sScan[512];
    const int t = threadIdx.x;
    const int b = blockIdx.x;
    const int base = b * BCAP;
    const int cnt_b = min(bktCur[b], BCAP);

    sHist[t] = 0;
    __syncthreads();
    for (int e = t; e < cnt_b; e += 512)
        atomicAdd(&sHist[arena[base + e] & 511], 1);
    __syncthreads();
    const int v = sHist[t];
    sScan[t] = v;
    __syncthreads();
    #pragma unroll
    for (int off = 1; off < 512; off <<= 1) {
        const int y = (t >= off) ? sScan[t - off] : 0;
        __syncthreads();
        sScan[t] += y;
        __syncthreads();
    }
    const int excl = sScan[t] - v;
    const int node = b * 512 + t;
    if (node < n) {
        meta[node] = make_int2(base + excl, v);
        const float d = (float)(1.0 / sqrt((double)(v + 1)));
        dis[node] = d;
        float2 xv = *(const float2*)(x + 2 * (size_t)node);
        xv.x *= d; xv.y *= d;
        *(float2*)(g0 + 2 * (size_t)node) = xv;
    }
    sHist[t] = excl;
    __syncthreads();
    for (int e = t; e < cnt_b; e += 512) {
        const int pv = arena[base + e];
        const int p = atomicAdd(&sHist[pv & 511], 1);
        csr_src[base + p] = pv >> 9;
    }
}

// =============== Layer 1: [N,2] -> g1h[N,16] (fp16). Wave per node. ==============
__global__ __launch_bounds__(256, 4)
void gcn_l1(const float* __restrict__ g0, const int2* __restrict__ meta,
            const int* __restrict__ csr_src, const float* __restrict__ dis,
            const float* __restrict__ W, const float* __restrict__ B,
            __half* __restrict__ g1h, int n, int nwaves) {
    const int lane = threadIdx.x & 63;
    const int wid = blockIdx.x * (blockDim.x >> 6) + (threadIdx.x >> 6);
    const int chunk = (n + nwaves - 1) / nwaves;
    const int n0 = wid * chunk, n1 = min(n0 + chunk, n);
    const int o = lane & 15;
    const float w0 = W[o], w1 = W[16 + o], bo = B[o];
    for (int node = n0; node < n1; ++node) {
        const int2 mt = meta[node];
        const int start = mt.x, m = mt.y;
        float a0 = 0.f, a1 = 0.f;
        for (int j = lane; j < m; j += 64) {
            const int s2 = csr_src[start + j];
            const float2 hv = *(const float2*)(g0 + 2 * (size_t)s2);
            a0 += hv.x;
            a1 += hv.y;
        }
        #pragma unroll
        for (int off = 32; off >= 1; off >>= 1) {
            a0 += __shfl_xor(a0, off);
            a1 += __shfl_xor(a1, off);
        }
        const float d0 = dis[node];
        const float2 hs = *(const float2*)(g0 + 2 * (size_t)node);
        a0 = (a0 + hs.x) * d0;
        a1 = (a1 + hs.y) * d0;
        if (lane < 16) {
            const float v = fmaxf(fmaf(a0, w0, fmaf(a1, w1, bo)), 0.f);
            g1h[(size_t)node * 16 + o] = __float2half(d0 * v);
        }
    }
}

// =============== AGG (fp16 table, C=16/32/64); optional fp16 agg output. =========
// Lane covers 8 channels (16B load). C16: LPR=2, 32 slots/round (1 round covers
// mean degree); C32: LPR=4; C64: LPR=8.
template <int C_IN, bool OUT_HALF>
__global__ __launch_bounds__(256, 6)
void agg_half_kernel(const __half* __restrict__ g_in, const int2* __restrict__ meta,
                     const int* __restrict__ csr_src, const float* __restrict__ dis,
                     void* __restrict__ agg_v, int n) {
    constexpr int LPR = C_IN / 8;                      // 2, 4, 8
    constexpr int EPW = 64 / LPR;                      // 32, 16, 8
    constexpr int LOGL = (LPR == 2) ? 1 : (LPR == 4) ? 2 : 3;
    constexpr int UNROLL = (EPW < 32) ? (32 / EPW) : 1;  // 1, 2, 4

    const int lane = threadIdx.x & 63;
    const int node = blockIdx.x * 4 + (threadIdx.x >> 6);
    if (node >= n) return;

    const int2 mt = meta[node];
    const int start = mt.x, m = mt.y;
    const int cb = (lane & (LPR - 1)) * 8;
    const int sub = lane >> LOGL;

    float a[8];
    #pragma unroll
    for (int q = 0; q < 8; ++q) a[q] = 0.f;

    for (int j = sub; j < m; j += UNROLL * EPW) {
        int ss[UNROLL];
        float mm[UNROLL];
        #pragma unroll
        for (int u = 0; u < UNROLL; ++u) {
            const int jj = j + u * EPW;
            const bool ok = jj < m;
            ss[u] = csr_src[start + (ok ? jj : 0)];
            mm[u] = ok ? 1.f : 0.f;
        }
        i32x4 hr[UNROLL];
        const __half* ap[UNROLL];
        #pragma unroll
        for (int u = 0; u < UNROLL; ++u) ap[u] = g_in + (size_t)ss[u] * C_IN + cb;
        #pragma unroll
        for (int u = 0; u < UNROLL; ++u)
            asm volatile("global_load_dwordx4 %0, %1, off"
                         : "=v"(hr[u]) : "v"(ap[u]) : "memory");
        asm volatile("s_waitcnt vmcnt(0)" ::: "memory");
        __builtin_amdgcn_sched_barrier(0);             // rule #18
        #pragma unroll
        for (int u = 0; u < UNROLL; ++u) {
            #pragma unroll
            for (int q = 0; q < 4; ++q) {
                const int wbits = hr[u][q];
                const __half2 h2 = *(const __half2*)&wbits;
                const float2 f2 = __half22float2(h2);
                a[2 * q]     = fmaf(mm[u], f2.x, a[2 * q]);
                a[2 * q + 1] = fmaf(mm[u], f2.y, a[2 * q + 1]);
            }
        }
    }
    #pragma unroll
    for (int off = 32; off >= LPR; off >>= 1) {
        #pragma unroll
        for (int q = 0; q < 8; ++q) a[q] += __shfl_xor(a[q], off);
    }
    if (lane < LPR) {
        const float d0 = dis[node];
        const __half* hp = g_in + (size_t)node * C_IN + cb;
        #pragma unroll
        for (int q = 0; q < 4; ++q) {
            const __half2 h2 = *(const __half2*)(hp + 2 * q);
            const float2 f2 = __half22float2(h2);
            a[2 * q]     = (a[2 * q]     + f2.x) * d0;
            a[2 * q + 1] = (a[2 * q + 1] + f2.y) * d0;
        }
        if constexpr (OUT_HALF) {
            f16x8 t;
            #pragma unroll
            for (int q = 0; q < 8; ++q) t[q] = (_Float16)a[q];
            *(f16x8*)((_Float16*)agg_v + (size_t)node * C_IN + cb) = t;
        } else {
            float* agg = (float*)agg_v;
            f32x4 t0, t1;
            t0.x = a[0]; t0.y = a[1]; t0.z = a[2]; t0.w = a[3];
            t1.x = a[4]; t1.y = a[5]; t1.z = a[6]; t1.w = a[7];
            *(f32x4*)&agg[(size_t)node * C_IN + cb] = t0;
            *(f32x4*)&agg[(size_t)node * C_IN + cb + 4] = t1;
        }
    }
}

// =============== GEMM (scalar, layers 2-3): out = dis*relu(agg @ W + B). =========
template <int C_IN, int C_OUT, bool OUT_HALF>
__global__ __launch_bounds__(256, 3)
void gemm_kernel(const float* __restrict__ agg, const float* __restrict__ W,
                 const float* __restrict__ Bias, const float* __restrict__ dis,
                 void* __restrict__ g_out_v, int n) {
    constexpr int QW = C_OUT / 16;
    constexpr int RPT = QW;
    constexpr int LOGQ = (QW == 8) ? 3 : (QW == 4) ? 2 : 1;
    constexpr int CH = C_IN / 4;
    constexpr int SA = 68;

    constexpr int W_BYTES = C_IN * C_OUT * 4 + C_OUT * 4;
    constexpr int R1 = (W_BYTES + 15) & ~15;
    constexpr int AT_BYTES = C_IN * SA * 4;
    __shared__ char smem[R1 + AT_BYTES];
    __shared__ float sDis[64];

    float* sW = (float*)smem;
    float* sB = sW + C_IN * C_OUT;
    float* sAt = (float*)(smem + R1);

    const int tid = threadIdx.x;
    const int base = blockIdx.x * 64;

    for (int i = tid; i < C_IN * C_OUT / 4; i += 256)
        ((f32x4*)sW)[i] = ((const f32x4*)W)[i];
    if (tid < C_OUT) sB[tid] = Bias[tid];
    {
        constexpr int RPP = 256 / CH;
        const int r = tid / CH, c0 = tid % CH;
        #pragma unroll
        for (int p = 0; p < 64 / RPP; ++p) {
            const int rr = p * RPP + r;
            const int node = base + rr;
            f32x4 v = {0.f, 0.f, 0.f, 0.f};
            if (node < n) v = *(const f32x4*)&agg[(size_t)node * C_IN + c0 * 4];
            sAt[(c0 * 4 + 0) * SA + rr] = v.x;
            sAt[(c0 * 4 + 1) * SA + rr] = v.y;
            sAt[(c0 * 4 + 2) * SA + rr] = v.z;
            sAt[(c0 * 4 + 3) * SA + rr] = v.w;
        }
    }
    if (tid < 64) sDis[tid] = (base + tid < n) ? dis[base + tid] : 0.f;
    __syncthreads();

    const int w = tid >> 6, l = tid & 63;
    const int j = l & (QW - 1);
    const int rg = l >> LOGQ;
    const int ob = w * (C_OUT / 4) + j * 4;

    f32x4 acc[RPT];
    {
        const f32x4 bv = *(const f32x4*)&sB[ob];
        #pragma unroll
        for (int r = 0; r < RPT; ++r) acc[r] = bv;
    }

    #pragma unroll 4
    for (int k = 0; k < C_IN; ++k) {
        const f32x4 wv = ((const f32x4*)sW)[k * (C_OUT / 4) + (ob >> 2)];
        float av[RPT];
        if constexpr (RPT == 4) {
            const f32x4 a0 = *(const f32x4*)&sAt[k * SA + rg * 4];
            av[0] = a0.x; av[1] = a0.y; av[2] = a0.z; av[3] = a0.w;
        } else {
            const float2 a0 = *(const float2*)&sAt[k * SA + rg * 2];
            av[0] = a0.x; av[1] = a0.y;
        }
        #pragma unroll
        for (int r = 0; r < RPT; ++r) {
            acc[r].x = fmaf(av[r], wv.x, acc[r].x);
            acc[r].y = fmaf(av[r], wv.y, acc[r].y);
            acc[r].z = fmaf(av[r], wv.z, acc[r].z);
            acc[r].w = fmaf(av[r], wv.w, acc[r].w);
        }
    }

    #pragma unroll
    for (int r = 0; r < RPT; ++r) {
        const int row = rg * RPT + r;
        const int node = base + row;
        if (node < n) {
            const float sd = sDis[row];
            const float o0 = sd * fmaxf(acc[r].x, 0.f);
            const float o1 = sd * fmaxf(acc[r].y, 0.f);
            const float o2 = sd * fmaxf(acc[r].z, 0.f);
            const float o3 = sd * fmaxf(acc[r].w, 0.f);
            if constexpr (OUT_HALF) {
                __half2 lo = __floats2half2_rn(o0, o1);
                __half2 hi = __floats2half2_rn(o2, o3);
                uint2 pk;
                pk.x = *(unsigned int*)&lo;
                pk.y = *(unsigned int*)&hi;
                *(uint2*)((__half*)g_out_v + (size_t)node * C_OUT + ob) = pk;
            } else {
                f32x4 o; o.x = o0; o.y = o1; o.z = o2; o.w = o3;
                *(f32x4*)((float*)g_out_v + (size_t)node * C_OUT + ob) = o;
            }
        }
    }
}

// =============== Layer-4 GEMM via MFMA + fused max-pool (R16-verified). ==========
__global__ __launch_bounds__(256)
void gemm4_mfma_kernel(const _Float16* __restrict__ aggh, const _Float16* __restrict__ Wpk,
                       const float* __restrict__ Bias, const int* __restrict__ batchv,
                       float* __restrict__ pooled, int n) {
    __shared__ float sP[4][16][132];
    __shared__ int sGb[64];

    const int tid = threadIdx.x;
    const int w = tid >> 6, l = tid & 63;
    const int base = blockIdx.x * 64;

    if (tid < 64) sGb[tid] = (base + tid < n) ? batchv[base + tid] : -1;

    int node_a = base + w * 16 + (l & 15);
    if (node_a >= n) node_a = n - 1;
    const int kb = l >> 4;
    const f16x4* rowp = (const f16x4*)(aggh + (size_t)node_a * 64);
    const f16x4 a00 = rowp[kb];
    const f16x4 a01 = rowp[4 + kb];
    const f16x4 a10 = rowp[8 + kb];
    const f16x4 a11 = rowp[12 + kb];
    const f16x8 a0 = __builtin_shufflevector(a00, a01, 0, 1, 2, 3, 4, 5, 6, 7);
    const f16x8 a1 = __builtin_shufflevector(a10, a11, 0, 1, 2, 3, 4, 5, 6, 7);

    f32x4 acc[8];
    #pragma unroll
    for (int ct = 0; ct < 8; ++ct) {
        f32x4 z = {0.f, 0.f, 0.f, 0.f};
        const f16x8 b0 = *(const f16x8*)(Wpk + ((ct * 2 + 0) * 64 + l) * 8);
        const f16x8 b1 = *(const f16x8*)(Wpk + ((ct * 2 + 1) * 64 + l) * 8);
        z = __builtin_amdgcn_mfma_f32_16x16x32_f16(a0, b0, z, 0, 0, 0);
        z = __builtin_amdgcn_mfma_f32_16x16x32_f16(a1, b1, z, 0, 0, 0);
        acc[ct] = z;
    }

    #pragma unroll
    for (int ct = 0; ct < 8; ++ct) {
        const float b = Bias[ct * 16 + (l & 15)];
        #pragma unroll
        for (int r = 0; r < 4; ++r) {
            const int m = (l >> 4) * 4 + r;
            sP[w][m][ct * 16 + (l & 15)] = fmaxf(acc[ct][r] + b, 0.f);
        }
    }
    __syncthreads();

    if (tid < 128) {
        const int c = tid;
        int curg = -1; float run = 0.f;
        for (int r2 = 0; r2 < 64; ++r2) {
            const int gb = sGb[r2];
            if (gb < 0) continue;
            const float v = sP[r2 >> 4][r2 & 15][c];
            if (gb != curg) {
                if (curg >= 0)
                    atomicMax((int*)&pooled[(size_t)curg * 128 + c], __float_as_int(run));
                curg = gb; run = v;
            } else {
                run = fmaxf(run, v);
            }
        }
        if (curg >= 0)
            atomicMax((int*)&pooled[(size_t)curg * 128 + c], __float_as_int(run));
    }
}

// ---------------- MLP head: relu(pooled @ W5 + b5) @ W6 + b6 ----------------
__global__ void mlp_kernel(const float* __restrict__ pooled,
                           const float* __restrict__ W5, const float* __restrict__ b5,
                           const float* __restrict__ W6, const float* __restrict__ b6,
                           float* __restrict__ out) {
    const int g = blockIdx.x;
    const int t = threadIdx.x;  // 64 threads
    __shared__ float row[128];
    __shared__ float hid[64];
    row[t] = pooled[g * 128 + t];
    row[64 + t] = pooled[g * 128 + 64 + t];
    __syncthreads();
    float v = b5[t];
    #pragma unroll 8
    for (int c = 0; c < 128; ++c) v = fmaf(row[c], W5[c * 64 + t], v);
    hid[t] = fmaxf(v, 0.f);
    __syncthreads();
    if (t < 10) {
        float o = b6[t];
        #pragma unroll 8
        for (int c = 0; c < 64; ++c) o = fmaf(hid[c], W6[c * 10 + t], o);
        out[g * 10 + t] = o;
    }
}

extern "C" void kernel_launch(void* const* d_in, const int* in_sizes, int n_in,
                              void* d_out, int out_size, void* d_ws, size_t ws_size,
                              hipStream_t stream) {
    const float* x     = (const float*)d_in[0];
    const int*   ei    = (const int*)d_in[1];
    const int*   batch = (const int*)d_in[2];
    const float* W1 = (const float*)d_in[3];  const float* b1 = (const float*)d_in[4];
    const float* W2 = (const float*)d_in[5];  const float* b2 = (const float*)d_in[6];
    const float* W3 = (const float*)d_in[7];  const float* b3 = (const float*)d_in[8];
    const float* W4 = (const float*)d_in[9];  const float* b4 = (const float*)d_in[10];
    const float* W5 = (const float*)d_in[11]; const float* b5 = (const float*)d_in[12];
    const float* W6 = (const float*)d_in[13]; const float* b6 = (const float*)d_in[14];
    float* out = (float*)d_out;

    const int N = in_sizes[0] / 2;       // 100000
    const int E = in_sizes[1] / 2;       // 1600000
    const int G = out_size / 10;         // 512

    // workspace layout
    char* p = (char*)d_ws;
    auto take = [&](size_t bytes) -> void* {
        void* r = (void*)p;
        p += (bytes + 255) & ~(size_t)255;
        return r;
    };
    int*       bktCur = (int*)take(NBKT * 4);
    int*       arena  = (int*)take((size_t)NBKT * BCAP * 4);
    int*       csr_src= (int*)take((size_t)NBKT * BCAP * 4);
    float*     dis    = (float*)take((size_t)N * 4);
    int2*      meta   = (int2*)take((size_t)N * 8);
    float*     g0     = (float*)take((size_t)N * 2 * 4);
    __half*    g1h    = (__half*)take((size_t)N * 16 * 2);
    __half*    g2h    = (__half*)take((size_t)N * 32 * 2);
    __half*    g3h    = (__half*)take((size_t)N * 64 * 2);
    float*     aggb   = (float*)take((size_t)N * 32 * 4);
    _Float16*  aggh   = (_Float16*)take((size_t)N * 64 * 2);
    _Float16*  Wpk    = (_Float16*)take(8192 * 2);
    float*     pooled = (float*)take((size_t)G * 128 * 4);

    // one fused init dispatch (replaces 2x hipMemsetAsync + prepack kernel)
    init_kernel<<<(512 * 128 + 255) / 256, 256, 0, stream>>>(bktCur, pooled, W4, Wpk);

    const int PBLK = (E + EPB - 1) / EPB;    // 391
    partition_kernel<<<PBLK, 256, 0, stream>>>(ei, E, bktCur, arena);
    bucket_csr_kernel<<<NBKT, 512, 0, stream>>>(arena, bktCur, csr_src, meta, dis, x, g0, N);

    gcn_l1<<<2048, 256, 0, stream>>>(g0, meta, csr_src, dis, W1, b1, g1h, N, 2048 * 4);

    const int ABLK = (N + 3) / 4;
    const int GBLK = (N + 63) / 64;

    agg_half_kernel<16, false><<<ABLK, 256, 0, stream>>>(g1h, meta, csr_src, dis, aggb, N);
    gemm_kernel<16, 32, true><<<GBLK, 256, 0, stream>>>(aggb, W2, b2, dis, g2h, N);

    agg_half_kernel<32, false><<<ABLK, 256, 0, stream>>>(g2h, meta, csr_src, dis, aggb, N);
    gemm_kernel<32, 64, true><<<GBLK, 256, 0, stream>>>(aggb, W3, b3, dis, g3h, N);

    agg_half_kernel<64, true><<<ABLK, 256, 0, stream>>>(g3h, meta, csr_src, dis, aggh, N);
    gemm4_mfma_kernel<<<GBLK, 256, 0, stream>>>(aggh, Wpk, b4, batch, pooled, N);

    mlp_kernel<<<G, 64, 0, stream>>>(pooled, W5, b5, W6, b6, out);
}

// Round 18
// 187.842 us; speedup vs baseline: 1.2482x; 1.2482x over previous
//
#include <hip/hip_runtime.h>
#include <hip/hip_fp16.h>

typedef __attribute__((ext_vector_type(4))) float f32x4;
typedef __attribute__((ext_vector_type(4))) int i32x4;
typedef _Float16 f16x8 __attribute__((ext_vector_type(8)));
typedef _Float16 f16x4 __attribute__((ext_vector_type(4)));

#define EPB 4096      // edges per partition block
#define NBKT 196      // ceil(100000/512) buckets of 512 nodes
#define BCAP 10240    // arena capacity per bucket (mean 8192, +22 sigma)

// =============== init: zero bktCur + pooled, prepack W4 ==========================
// W4 B-fragment: elem i of lane l holds B[k][n], n = ct*16+(l&15),
// k = kk*32 + 4*(l>>4) + (i&3) + 16*(i>>2)   [R16-verified]
__global__ __launch_bounds__(256)
void init_kernel(int* __restrict__ bktCur, float* __restrict__ pooled,
                 const float* __restrict__ W, _Float16* __restrict__ Wpk) {
    const int gid = blockIdx.x * 256 + threadIdx.x;
    if (gid < NBKT) bktCur[gid] = 0;
    if (gid < 512 * 128) pooled[gid] = 0.f;
    if (gid < 8192) {
        const int i = gid & 7;
        const int l = (gid >> 3) & 63;
        const int kk = (gid >> 9) & 1;
        const int ct = gid >> 10;
        const int k = kk * 32 + 4 * (l >> 4) + (i & 3) + 16 * (i >> 2);
        const int col = ct * 16 + (l & 15);
        Wpk[gid] = (_Float16)W[k * 128 + col];
    }
}

// =============== Phase B: partition edges into per-bucket arenas ================
__global__ __launch_bounds__(256)
void partition_kernel(const int* __restrict__ ei, int E,
                      int* __restrict__ bktCur, int* __restrict__ arena) {
    __shared__ int sHist[256];
    __shared__ int sScan[256];
    __shared__ int sAdj[256];
    __shared__ int2 sEdges[EPB];     // 32 KB staging
    const int t = threadIdx.x;
    const int e0 = blockIdx.x * EPB;
    const int ecnt = min(EPB, E - e0);
    const int* src = ei;
    const int* dst = ei + E;

    sHist[t] = 0;
    __syncthreads();
    for (int k = t; k < ecnt; k += 256) {
        const int s = src[e0 + k], d = dst[e0 + k];
        sEdges[k] = make_int2(s, d);
        atomicAdd(&sHist[d >> 9], 1);
    }
    __syncthreads();
    const int v = sHist[t];
    sScan[t] = v;
    __syncthreads();
    #pragma unroll
    for (int off = 1; off < 256; off <<= 1) {
        const int y = (t >= off) ? sScan[t - off] : 0;
        __syncthreads();
        sScan[t] += y;
        __syncthreads();
    }
    const int excl = sScan[t] - v;
    if (t < NBKT && v > 0) {
        const int g = atomicAdd(&bktCur[t], v);
        sAdj[t] = t * BCAP + g - excl;
    }
    sHist[t] = excl;
    __syncthreads();
    for (int k = t; k < ecnt; k += 256) {
        const int2 e = sEdges[k];
        const int b = e.y >> 9;
        const int p = atomicAdd(&sHist[b], 1);
        arena[sAdj[b] + p] = (e.x << 9) | (e.y & 511);
    }
}

// =============== Phase C: per-bucket CSR build + meta + dis + g0 = dis*x =========
__global__ __launch_bounds__(512)
void bucket_csr_kernel(const int* __restrict__ arena, const int* __restrict__ bktCur,
                       int* __restrict__ csr_src, int2* __restrict__ meta,
                       float* __restrict__ dis, const float* __restrict__ x,
                       float* __restrict__ g0, int n) {
    __shared__ int sHist[512];
    __shared__ int sScan[512];
    const int t = threadIdx.x;
    const int b = blockIdx.x;
    const int base = b * BCAP;
    const int cnt_b = min(bktCur[b], BCAP);

    sHist[t] = 0;
    __syncthreads();
    for (int e = t; e < cnt_b; e += 512)
        atomicAdd(&sHist[arena[base + e] & 511], 1);
    __syncthreads();
    const int v = sHist[t];
    sScan[t] = v;
    __syncthreads();
    #pragma unroll
    for (int off = 1; off < 512; off <<= 1) {
        const int y = (t >= off) ? sScan[t - off] : 0;
        __syncthreads();
        sScan[t] += y;
        __syncthreads();
    }
    const int excl = sScan[t] - v;
    const int node = b * 512 + t;
    if (node < n) {
        meta[node] = make_int2(base + excl, v);
        const float d = (float)(1.0 / sqrt((double)(v + 1)));
        dis[node] = d;
        float2 xv = *(const float2*)(x + 2 * (size_t)node);
        xv.x *= d; xv.y *= d;
        *(float2*)(g0 + 2 * (size_t)node) = xv;
    }
    sHist[t] = excl;
    __syncthreads();
    for (int e = t; e < cnt_b; e += 512) {
        const int pv = arena[base + e];
        const int p = atomicAdd(&sHist[pv & 511], 1);
        csr_src[base + p] = pv >> 9;
    }
}

// =============== Layer 1: [N,2] -> g1h[N,16] (fp16). Wave per node. ==============
__global__ __launch_bounds__(256, 4)
void gcn_l1(const float* __restrict__ g0, const int2* __restrict__ meta,
            const int* __restrict__ csr_src, const float* __restrict__ dis,
            const float* __restrict__ W, const float* __restrict__ B,
            __half* __restrict__ g1h, int n, int nwaves) {
    const int lane = threadIdx.x & 63;
    const int wid = blockIdx.x * (blockDim.x >> 6) + (threadIdx.x >> 6);
    const int chunk = (n + nwaves - 1) / nwaves;
    const int n0 = wid * chunk, n1 = min(n0 + chunk, n);
    const int o = lane & 15;
    const float w0 = W[o], w1 = W[16 + o], bo = B[o];
    for (int node = n0; node < n1; ++node) {
        const int2 mt = meta[node];
        const int start = mt.x, m = mt.y;
        float a0 = 0.f, a1 = 0.f;
        for (int j = lane; j < m; j += 64) {
            const int s2 = csr_src[start + j];
            const float2 hv = *(const float2*)(g0 + 2 * (size_t)s2);
            a0 += hv.x;
            a1 += hv.y;
        }
        #pragma unroll
        for (int off = 32; off >= 1; off >>= 1) {
            a0 += __shfl_xor(a0, off);
            a1 += __shfl_xor(a1, off);
        }
        const float d0 = dis[node];
        const float2 hs = *(const float2*)(g0 + 2 * (size_t)node);
        a0 = (a0 + hs.x) * d0;
        a1 = (a1 + hs.y) * d0;
        if (lane < 16) {
            const float v = fmaxf(fmaf(a0, w0, fmaf(a1, w1, bo)), 0.f);
            g1h[(size_t)node * 16 + o] = __float2half(d0 * v);
        }
    }
}

// =============== AGG group kernel (fp16 table): NO cross-lane reduce. ============
// R17 lesson: one-node-per-wave spent ~200 instrs/node (80-op butterfly) for
// 272 useful MACs. Here an LPR-lane group owns ONE node exclusively (C16: 32
// nodes/wave); each lane walks its node's edges with an 8-deep asm gather batch
// (latency hidden by batching, not lane-spread). Zero shuffles.
template <int C_IN, bool OUT_HALF>
__global__ __launch_bounds__(256, 6)
void agg_group_kernel(const __half* __restrict__ g_in, const int2* __restrict__ meta,
                      const int* __restrict__ csr_src, const float* __restrict__ dis,
                      void* __restrict__ agg_v, int n) {
    constexpr int LPR = C_IN / 8;                      // lanes per node: 2, 4, 8
    constexpr int GPW = 64 / LPR;                      // nodes per wave: 32, 16, 8

    const int lane = threadIdx.x & 63;
    const int wv = threadIdx.x >> 6;
    const int grp = lane / LPR;
    const int sl  = lane % LPR;
    const int node = ((size_t)blockIdx.x * 4 + wv) * GPW + grp;
    const bool valid = node < n;

    const int2 mt = valid ? meta[node] : make_int2(0, 0);
    const int start = mt.x, m = mt.y;
    const int cb = sl * 8;

    float a[8];
    #pragma unroll
    for (int q = 0; q < 8; ++q) a[q] = 0.f;

    for (int j = 0; j < m; j += 8) {
        int ss[8];
        float mm[8];
        #pragma unroll
        for (int u = 0; u < 8; ++u) {
            const int jj = j + u;
            const bool ok = jj < m;
            ss[u] = csr_src[start + (ok ? jj : 0)];    // contiguous, L2-hot
            mm[u] = ok ? 1.f : 0.f;
        }
        i32x4 hr[8];
        const __half* ap[8];
        #pragma unroll
        for (int u = 0; u < 8; ++u) ap[u] = g_in + (size_t)ss[u] * C_IN + cb;
        #pragma unroll
        for (int u = 0; u < 8; ++u)
            asm volatile("global_load_dwordx4 %0, %1, off"
                         : "=v"(hr[u]) : "v"(ap[u]) : "memory");
        asm volatile("s_waitcnt vmcnt(0)" ::: "memory");
        __builtin_amdgcn_sched_barrier(0);             // rule #18
        #pragma unroll
        for (int u = 0; u < 8; ++u) {
            #pragma unroll
            for (int q = 0; q < 4; ++q) {
                const int wbits = hr[u][q];
                const __half2 h2 = *(const __half2*)&wbits;
                const float2 f2 = __half22float2(h2);
                a[2 * q]     = fmaf(mm[u], f2.x, a[2 * q]);
                a[2 * q + 1] = fmaf(mm[u], f2.y, a[2 * q + 1]);
            }
        }
    }

    if (valid) {
        const float d0 = dis[node];
        const __half* hp = g_in + (size_t)node * C_IN + cb;
        #pragma unroll
        for (int q = 0; q < 4; ++q) {
            const __half2 h2 = *(const __half2*)(hp + 2 * q);
            const float2 f2 = __half22float2(h2);
            a[2 * q]     = (a[2 * q]     + f2.x) * d0;
            a[2 * q + 1] = (a[2 * q + 1] + f2.y) * d0;
        }
        if constexpr (OUT_HALF) {
            f16x8 t;
            #pragma unroll
            for (int q = 0; q < 8; ++q) t[q] = (_Float16)a[q];
            *(f16x8*)((_Float16*)agg_v + (size_t)node * C_IN + cb) = t;
        } else {
            float* agg = (float*)agg_v;
            f32x4 t0, t1;
            t0.x = a[0]; t0.y = a[1]; t0.z = a[2]; t0.w = a[3];
            t1.x = a[4]; t1.y = a[5]; t1.z = a[6]; t1.w = a[7];
            *(f32x4*)&agg[(size_t)node * C_IN + cb] = t0;
            *(f32x4*)&agg[(size_t)node * C_IN + cb + 4] = t1;
        }
    }
}

// =============== GEMM (scalar, layers 2-3): out = dis*relu(agg @ W + B). =========
template <int C_IN, int C_OUT, bool OUT_HALF>
__global__ __launch_bounds__(256, 3)
void gemm_kernel(const float* __restrict__ agg, const float* __restrict__ W,
                 const float* __restrict__ Bias, const float* __restrict__ dis,
                 void* __restrict__ g_out_v, int n) {
    constexpr int QW = C_OUT / 16;
    constexpr int RPT = QW;
    constexpr int LOGQ = (QW == 8) ? 3 : (QW == 4) ? 2 : 1;
    constexpr int CH = C_IN / 4;
    constexpr int SA = 68;

    constexpr int W_BYTES = C_IN * C_OUT * 4 + C_OUT * 4;
    constexpr int R1 = (W_BYTES + 15) & ~15;
    constexpr int AT_BYTES = C_IN * SA * 4;
    __shared__ char smem[R1 + AT_BYTES];
    __shared__ float sDis[64];

    float* sW = (float*)smem;
    float* sB = sW + C_IN * C_OUT;
    float* sAt = (float*)(smem + R1);

    const int tid = threadIdx.x;
    const int base = blockIdx.x * 64;

    for (int i = tid; i < C_IN * C_OUT / 4; i += 256)
        ((f32x4*)sW)[i] = ((const f32x4*)W)[i];
    if (tid < C_OUT) sB[tid] = Bias[tid];
    {
        constexpr int RPP = 256 / CH;
        const int r = tid / CH, c0 = tid % CH;
        #pragma unroll
        for (int p = 0; p < 64 / RPP; ++p) {
            const int rr = p * RPP + r;
            const int node = base + rr;
            f32x4 v = {0.f, 0.f, 0.f, 0.f};
            if (node < n) v = *(const f32x4*)&agg[(size_t)node * C_IN + c0 * 4];
            sAt[(c0 * 4 + 0) * SA + rr] = v.x;
            sAt[(c0 * 4 + 1) * SA + rr] = v.y;
            sAt[(c0 * 4 + 2) * SA + rr] = v.z;
            sAt[(c0 * 4 + 3) * SA + rr] = v.w;
        }
    }
    if (tid < 64) sDis[tid] = (base + tid < n) ? dis[base + tid] : 0.f;
    __syncthreads();

    const int w = tid >> 6, l = tid & 63;
    const int j = l & (QW - 1);
    const int rg = l >> LOGQ;
    const int ob = w * (C_OUT / 4) + j * 4;

    f32x4 acc[RPT];
    {
        const f32x4 bv = *(const f32x4*)&sB[ob];
        #pragma unroll
        for (int r = 0; r < RPT; ++r) acc[r] = bv;
    }

    #pragma unroll 4
    for (int k = 0; k < C_IN; ++k) {
        const f32x4 wv = ((const f32x4*)sW)[k * (C_OUT / 4) + (ob >> 2)];
        float av[RPT];
        if constexpr (RPT == 4) {
            const f32x4 a0 = *(const f32x4*)&sAt[k * SA + rg * 4];
            av[0] = a0.x; av[1] = a0.y; av[2] = a0.z; av[3] = a0.w;
        } else {
            const float2 a0 = *(const float2*)&sAt[k * SA + rg * 2];
            av[0] = a0.x; av[1] = a0.y;
        }
        #pragma unroll
        for (int r = 0; r < RPT; ++r) {
            acc[r].x = fmaf(av[r], wv.x, acc[r].x);
            acc[r].y = fmaf(av[r], wv.y, acc[r].y);
            acc[r].z = fmaf(av[r], wv.z, acc[r].z);
            acc[r].w = fmaf(av[r], wv.w, acc[r].w);
        }
    }

    #pragma unroll
    for (int r = 0; r < RPT; ++r) {
        const int row = rg * RPT + r;
        const int node = base + row;
        if (node < n) {
            const float sd = sDis[row];
            const float o0 = sd * fmaxf(acc[r].x, 0.f);
            const float o1 = sd * fmaxf(acc[r].y, 0.f);
            const float o2 = sd * fmaxf(acc[r].z, 0.f);
            const float o3 = sd * fmaxf(acc[r].w, 0.f);
            if constexpr (OUT_HALF) {
                __half2 lo = __floats2half2_rn(o0, o1);
                __half2 hi = __floats2half2_rn(o2, o3);
                uint2 pk;
                pk.x = *(unsigned int*)&lo;
                pk.y = *(unsigned int*)&hi;
                *(uint2*)((__half*)g_out_v + (size_t)node * C_OUT + ob) = pk;
            } else {
                f32x4 o; o.x = o0; o.y = o1; o.z = o2; o.w = o3;
                *(f32x4*)((float*)g_out_v + (size_t)node * C_OUT + ob) = o;
            }
        }
    }
}

// =============== Layer-4 GEMM via MFMA + fused max-pool (R16-verified). ==========
__global__ __launch_bounds__(256)
void gemm4_mfma_kernel(const _Float16* __restrict__ aggh, const _Float16* __restrict__ Wpk,
                       const float* __restrict__ Bias, const int* __restrict__ batchv,
                       float* __restrict__ pooled, int n) {
    __shared__ float sP[4][16][132];
    __shared__ int sGb[64];

    const int tid = threadIdx.x;
    const int w = tid >> 6, l = tid & 63;
    const int base = blockIdx.x * 64;

    if (tid < 64) sGb[tid] = (base + tid < n) ? batchv[base + tid] : -1;

    int node_a = base + w * 16 + (l & 15);
    if (node_a >= n) node_a = n - 1;
    const int kb = l >> 4;
    const f16x4* rowp = (const f16x4*)(aggh + (size_t)node_a * 64);
    const f16x4 a00 = rowp[kb];
    const f16x4 a01 = rowp[4 + kb];
    const f16x4 a10 = rowp[8 + kb];
    const f16x4 a11 = rowp[12 + kb];
    const f16x8 a0 = __builtin_shufflevector(a00, a01, 0, 1, 2, 3, 4, 5, 6, 7);
    const f16x8 a1 = __builtin_shufflevector(a10, a11, 0, 1, 2, 3, 4, 5, 6, 7);

    f32x4 acc[8];
    #pragma unroll
    for (int ct = 0; ct < 8; ++ct) {
        f32x4 z = {0.f, 0.f, 0.f, 0.f};
        const f16x8 b0 = *(const f16x8*)(Wpk + ((ct * 2 + 0) * 64 + l) * 8);
        const f16x8 b1 = *(const f16x8*)(Wpk + ((ct * 2 + 1) * 64 + l) * 8);
        z = __builtin_amdgcn_mfma_f32_16x16x32_f16(a0, b0, z, 0, 0, 0);
        z = __builtin_amdgcn_mfma_f32_16x16x32_f16(a1, b1, z, 0, 0, 0);
        acc[ct] = z;
    }

    #pragma unroll
    for (int ct = 0; ct < 8; ++ct) {
        const float b = Bias[ct * 16 + (l & 15)];
        #pragma unroll
        for (int r = 0; r < 4; ++r) {
            const int m = (l >> 4) * 4 + r;
            sP[w][m][ct * 16 + (l & 15)] = fmaxf(acc[ct][r] + b, 0.f);
        }
    }
    __syncthreads();

    if (tid < 128) {
        const int c = tid;
        int curg = -1; float run = 0.f;
        for (int r2 = 0; r2 < 64; ++r2) {
            const int gb = sGb[r2];
            if (gb < 0) continue;
            const float v = sP[r2 >> 4][r2 & 15][c];
            if (gb != curg) {
                if (curg >= 0)
                    atomicMax((int*)&pooled[(size_t)curg * 128 + c], __float_as_int(run));
                curg = gb; run = v;
            } else {
                run = fmaxf(run, v);
            }
        }
        if (curg >= 0)
            atomicMax((int*)&pooled[(size_t)curg * 128 + c], __float_as_int(run));
    }
}

// ---------------- MLP head: relu(pooled @ W5 + b5) @ W6 + b6 ----------------
__global__ void mlp_kernel(const float* __restrict__ pooled,
                           const float* __restrict__ W5, const float* __restrict__ b5,
                           const float* __restrict__ W6, const float* __restrict__ b6,
                           float* __restrict__ out) {
    const int g = blockIdx.x;
    const int t = threadIdx.x;  // 64 threads
    __shared__ float row[128];
    __shared__ float hid[64];
    row[t] = pooled[g * 128 + t];
    row[64 + t] = pooled[g * 128 + 64 + t];
    __syncthreads();
    float v = b5[t];
    #pragma unroll 8
    for (int c = 0; c < 128; ++c) v = fmaf(row[c], W5[c * 64 + t], v);
    hid[t] = fmaxf(v, 0.f);
    __syncthreads();
    if (t < 10) {
        float o = b6[t];
        #pragma unroll 8
        for (int c = 0; c < 64; ++c) o = fmaf(hid[c], W6[c * 10 + t], o);
        out[g * 10 + t] = o;
    }
}

extern "C" void kernel_launch(void* const* d_in, const int* in_sizes, int n_in,
                              void* d_out, int out_size, void* d_ws, size_t ws_size,
                              hipStream_t stream) {
    const float* x     = (const float*)d_in[0];
    const int*   ei    = (const int*)d_in[1];
    const int*   batch = (const int*)d_in[2];
    const float* W1 = (const float*)d_in[3];  const float* b1 = (const float*)d_in[4];
    const float* W2 = (const float*)d_in[5];  const float* b2 = (const float*)d_in[6];
    const float* W3 = (const float*)d_in[7];  const float* b3 = (const float*)d_in[8];
    const float* W4 = (const float*)d_in[9];  const float* b4 = (const float*)d_in[10];
    const float* W5 = (const float*)d_in[11]; const float* b5 = (const float*)d_in[12];
    const float* W6 = (const float*)d_in[13]; const float* b6 = (const float*)d_in[14];
    float* out = (float*)d_out;

    const int N = in_sizes[0] / 2;       // 100000
    const int E = in_sizes[1] / 2;       // 1600000
    const int G = out_size / 10;         // 512

    // workspace layout
    char* p = (char*)d_ws;
    auto take = [&](size_t bytes) -> void* {
        void* r = (void*)p;
        p += (bytes + 255) & ~(size_t)255;
        return r;
    };
    int*       bktCur = (int*)take(NBKT * 4);
    int*       arena  = (int*)take((size_t)NBKT * BCAP * 4);
    int*       csr_src= (int*)take((size_t)NBKT * BCAP * 4);
    float*     dis    = (float*)take((size_t)N * 4);
    int2*      meta   = (int2*)take((size_t)N * 8);
    float*     g0     = (float*)take((size_t)N * 2 * 4);
    __half*    g1h    = (__half*)take((size_t)N * 16 * 2);
    __half*    g2h    = (__half*)take((size_t)N * 32 * 2);
    __half*    g3h    = (__half*)take((size_t)N * 64 * 2);
    float*     aggb   = (float*)take((size_t)N * 32 * 4);
    _Float16*  aggh   = (_Float16*)take((size_t)N * 64 * 2);
    _Float16*  Wpk    = (_Float16*)take(8192 * 2);
    float*     pooled = (float*)take((size_t)G * 128 * 4);

    init_kernel<<<(512 * 128 + 255) / 256, 256, 0, stream>>>(bktCur, pooled, W4, Wpk);

    const int PBLK = (E + EPB - 1) / EPB;    // 391
    partition_kernel<<<PBLK, 256, 0, stream>>>(ei, E, bktCur, arena);
    bucket_csr_kernel<<<NBKT, 512, 0, stream>>>(arena, bktCur, csr_src, meta, dis, x, g0, N);

    gcn_l1<<<2048, 256, 0, stream>>>(g0, meta, csr_src, dis, W1, b1, g1h, N, 2048 * 4);

    const int GBLK = (N + 63) / 64;

    // nodes per block: C16 -> 128, C32 -> 64, C64 -> 32
    agg_group_kernel<16, false><<<(N + 127) / 128, 256, 0, stream>>>(g1h, meta, csr_src, dis, aggb, N);
    gemm_kernel<16, 32, true><<<GBLK, 256, 0, stream>>>(aggb, W2, b2, dis, g2h, N);

    agg_group_kernel<32, false><<<(N + 63) / 64, 256, 0, stream>>>(g2h, meta, csr_src, dis, aggb, N);
    gemm_kernel<32, 64, true><<<GBLK, 256, 0, stream>>>(aggb, W3, b3, dis, g3h, N);

    agg_group_kernel<64, true><<<(N + 31) / 32, 256, 0, stream>>>(g3h, meta, csr_src, dis, aggh, N);
    gemm4_mfma_kernel<<<GBLK, 256, 0, stream>>>(aggh, Wpk, b4, batch, pooled, N);

    mlp_kernel<<<G, 64, 0, stream>>>(pooled, W5, b5, W6, b6, out);
}

// Round 19
// 169.745 us; speedup vs baseline: 1.3813x; 1.1066x over previous
//
#include <hip/hip_runtime.h>
#include <hip/hip_fp16.h>

typedef __attribute__((ext_vector_type(4))) float f32x4;
typedef __attribute__((ext_vector_type(2))) float f32x2;
typedef __attribute__((ext_vector_type(4))) int i32x4;
typedef _Float16 f16x8 __attribute__((ext_vector_type(8)));
typedef _Float16 f16x4 __attribute__((ext_vector_type(4)));

#define EPB 4096      // edges per partition block
#define NBKT 196      // ceil(100000/512) buckets of 512 nodes
#define BCAP 10240    // arena capacity per bucket

// =============== init: zero bktCur + pooled, prepack W4 ==========================
// W4 B-fragment [R16-verified]: elem i of lane l holds B[k][n], n = ct*16+(l&15),
// k = kk*32 + 4*(l>>4) + (i&3) + 16*(i>>2)
__global__ __launch_bounds__(256)
void init_kernel(int* __restrict__ bktCur, float* __restrict__ pooled,
                 const float* __restrict__ W, _Float16* __restrict__ Wpk) {
    const int gid = blockIdx.x * 256 + threadIdx.x;
    if (gid < NBKT) bktCur[gid] = 0;
    if (gid < 512 * 128) pooled[gid] = 0.f;
    if (gid < 8192) {
        const int i = gid & 7;
        const int l = (gid >> 3) & 63;
        const int kk = (gid >> 9) & 1;
        const int ct = gid >> 10;
        const int k = kk * 32 + 4 * (l >> 4) + (i & 3) + 16 * (i >> 2);
        const int col = ct * 16 + (l & 15);
        Wpk[gid] = (_Float16)W[k * 128 + col];
    }
}

// =============== Phase B: partition edges into per-bucket arenas ================
__global__ __launch_bounds__(256)
void partition_kernel(const int* __restrict__ ei, int E,
                      int* __restrict__ bktCur, int* __restrict__ arena) {
    __shared__ int sHist[256];
    __shared__ int sScan[256];
    __shared__ int sAdj[256];
    __shared__ int2 sEdges[EPB];     // 32 KB staging
    const int t = threadIdx.x;
    const int e0 = blockIdx.x * EPB;
    const int ecnt = min(EPB, E - e0);
    const int* src = ei;
    const int* dst = ei + E;

    sHist[t] = 0;
    __syncthreads();
    for (int k = t; k < ecnt; k += 256) {
        const int s = src[e0 + k], d = dst[e0 + k];
        sEdges[k] = make_int2(s, d);
        atomicAdd(&sHist[d >> 9], 1);
    }
    __syncthreads();
    const int v = sHist[t];
    sScan[t] = v;
    __syncthreads();
    #pragma unroll
    for (int off = 1; off < 256; off <<= 1) {
        const int y = (t >= off) ? sScan[t - off] : 0;
        __syncthreads();
        sScan[t] += y;
        __syncthreads();
    }
    const int excl = sScan[t] - v;
    if (t < NBKT && v > 0) {
        const int g = atomicAdd(&bktCur[t], v);
        sAdj[t] = t * BCAP + g - excl;
    }
    sHist[t] = excl;
    __syncthreads();
    for (int k = t; k < ecnt; k += 256) {
        const int2 e = sEdges[k];
        const int b = e.y >> 9;
        const int p = atomicAdd(&sHist[b], 1);
        arena[sAdj[b] + p] = (e.x << 9) | (e.y & 511);
    }
}

// =============== Phase C: per-bucket CSR build + meta + dis + g0 = dis*x =========
__global__ __launch_bounds__(512)
void bucket_csr_kernel(const int* __restrict__ arena, const int* __restrict__ bktCur,
                       int* __restrict__ csr_src, int2* __restrict__ meta,
                       float* __restrict__ dis, const float* __restrict__ x,
                       float* __restrict__ g0, int n) {
    __shared__ int sHist[512];
    __shared__ int sScan[512];
    const int t = threadIdx.x;
    const int b = blockIdx.x;
    const int base = b * BCAP;
    const int cnt_b = min(bktCur[b], BCAP);

    sHist[t] = 0;
    __syncthreads();
    for (int e = t; e < cnt_b; e += 512)
        atomicAdd(&sHist[arena[base + e] & 511], 1);
    __syncthreads();
    const int v = sHist[t];
    sScan[t] = v;
    __syncthreads();
    #pragma unroll
    for (int off = 1; off < 512; off <<= 1) {
        const int y = (t >= off) ? sScan[t - off] : 0;
        __syncthreads();
        sScan[t] += y;
        __syncthreads();
    }
    const int excl = sScan[t] - v;
    const int node = b * 512 + t;
    if (node < n) {
        meta[node] = make_int2(base + excl, v);
        const float d = (float)(1.0 / sqrt((double)(v + 1)));
        dis[node] = d;
        float2 xv = *(const float2*)(x + 2 * (size_t)node);
        xv.x *= d; xv.y *= d;
        *(float2*)(g0 + 2 * (size_t)node) = xv;
    }
    sHist[t] = excl;
    __syncthreads();
    for (int e = t; e < cnt_b; e += 512) {
        const int pv = arena[base + e];
        const int p = atomicAdd(&sHist[pv & 511], 1);
        csr_src[base + p] = pv >> 9;
    }
}

// =============== Layer 1: [N,2] -> g1h[N,16] (fp16). LANE per node, no shuffles. ==
__global__ __launch_bounds__(256, 6)
void gcn_l1_lane(const float* __restrict__ g0, const int2* __restrict__ meta,
                 const int* __restrict__ csr_src, const float* __restrict__ dis,
                 const float* __restrict__ W, const float* __restrict__ B,
                 __half* __restrict__ g1h, int n) {
    __shared__ float sW[32];
    __shared__ float sB[16];
    const int tid = threadIdx.x;
    if (tid < 32) sW[tid] = W[tid];
    if (tid < 16) sB[tid] = B[tid];
    __syncthreads();
    const int node = blockIdx.x * 256 + tid;
    if (node >= n) return;
    const int2 mt = meta[node];
    const int start = mt.x, m = mt.y;
    float a0 = 0.f, a1 = 0.f;
    for (int j = 0; j < m; j += 8) {
        int ss[8]; float mm[8];
        #pragma unroll
        for (int u = 0; u < 8; ++u) {
            const int jj = j + u;
            const bool ok = jj < m;
            ss[u] = csr_src[start + (ok ? jj : 0)];
            mm[u] = ok ? 1.f : 0.f;
        }
        f32x2 hv[8];
        const float* ap[8];
        #pragma unroll
        for (int u = 0; u < 8; ++u) ap[u] = g0 + 2 * (size_t)ss[u];
        #pragma unroll
        for (int u = 0; u < 8; ++u)
            asm volatile("global_load_dwordx2 %0, %1, off"
                         : "=v"(hv[u]) : "v"(ap[u]) : "memory");
        asm volatile("s_waitcnt vmcnt(0)" ::: "memory");
        __builtin_amdgcn_sched_barrier(0);             // rule #18
        #pragma unroll
        for (int u = 0; u < 8; ++u) {
            a0 = fmaf(mm[u], hv[u].x, a0);
            a1 = fmaf(mm[u], hv[u].y, a1);
        }
    }
    const float d0 = dis[node];
    const float2 hs = *(const float2*)(g0 + 2 * (size_t)node);
    a0 = (a0 + hs.x) * d0;
    a1 = (a1 + hs.y) * d0;
    f16x8 o0, o1;
    #pragma unroll
    for (int o = 0; o < 8; ++o) {
        const float v0 = fmaxf(fmaf(a0, sW[o], fmaf(a1, sW[16 + o], sB[o])), 0.f);
        const float v1 = fmaxf(fmaf(a0, sW[o + 8], fmaf(a1, sW[24 + o], sB[o + 8])), 0.f);
        o0[o] = (_Float16)(d0 * v0);
        o1[o] = (_Float16)(d0 * v1);
    }
    *(f16x8*)((_Float16*)g1h + (size_t)node * 16) = o0;
    *(f16x8*)((_Float16*)g1h + (size_t)node * 16 + 8) = o1;
}

// =============== AGG group kernel (layer 2 only; R18-proven). =====================
template <int C_IN, bool OUT_HALF>
__global__ __launch_bounds__(256, 6)
void agg_group_kernel(const __half* __restrict__ g_in, const int2* __restrict__ meta,
                      const int* __restrict__ csr_src, const float* __restrict__ dis,
                      void* __restrict__ agg_v, int n) {
    constexpr int LPR = C_IN / 8;
    constexpr int GPW = 64 / LPR;

    const int lane = threadIdx.x & 63;
    const int wv = threadIdx.x >> 6;
    const int grp = lane / LPR;
    const int sl  = lane % LPR;
    const int node = ((size_t)blockIdx.x * 4 + wv) * GPW + grp;
    const bool valid = node < n;

    const int2 mt = valid ? meta[node] : make_int2(0, 0);
    const int start = mt.x, m = mt.y;
    const int cb = sl * 8;

    float a[8];
    #pragma unroll
    for (int q = 0; q < 8; ++q) a[q] = 0.f;

    for (int j = 0; j < m; j += 8) {
        int ss[8]; float mm[8];
        #pragma unroll
        for (int u = 0; u < 8; ++u) {
            const int jj = j + u;
            const bool ok = jj < m;
            ss[u] = csr_src[start + (ok ? jj : 0)];
            mm[u] = ok ? 1.f : 0.f;
        }
        i32x4 hr[8];
        const __half* ap[8];
        #pragma unroll
        for (int u = 0; u < 8; ++u) ap[u] = g_in + (size_t)ss[u] * C_IN + cb;
        #pragma unroll
        for (int u = 0; u < 8; ++u)
            asm volatile("global_load_dwordx4 %0, %1, off"
                         : "=v"(hr[u]) : "v"(ap[u]) : "memory");
        asm volatile("s_waitcnt vmcnt(0)" ::: "memory");
        __builtin_amdgcn_sched_barrier(0);             // rule #18
        #pragma unroll
        for (int u = 0; u < 8; ++u) {
            #pragma unroll
            for (int q = 0; q < 4; ++q) {
                const int wbits = hr[u][q];
                const __half2 h2 = *(const __half2*)&wbits;
                const float2 f2 = __half22float2(h2);
                a[2 * q]     = fmaf(mm[u], f2.x, a[2 * q]);
                a[2 * q + 1] = fmaf(mm[u], f2.y, a[2 * q + 1]);
            }
        }
    }

    if (valid) {
        const float d0 = dis[node];
        const __half* hp = g_in + (size_t)node * C_IN + cb;
        #pragma unroll
        for (int q = 0; q < 4; ++q) {
            const __half2 h2 = *(const __half2*)(hp + 2 * q);
            const float2 f2 = __half22float2(h2);
            a[2 * q]     = (a[2 * q]     + f2.x) * d0;
            a[2 * q + 1] = (a[2 * q + 1] + f2.y) * d0;
        }
        if constexpr (OUT_HALF) {
            f16x8 t;
            #pragma unroll
            for (int q = 0; q < 8; ++q) t[q] = (_Float16)a[q];
            *(f16x8*)((_Float16*)agg_v + (size_t)node * C_IN + cb) = t;
        } else {
            float* agg = (float*)agg_v;
            f32x4 t0, t1;
            t0.x = a[0]; t0.y = a[1]; t0.z = a[2]; t0.w = a[3];
            t1.x = a[4]; t1.y = a[5]; t1.z = a[6]; t1.w = a[7];
            *(f32x4*)&agg[(size_t)node * C_IN + cb] = t0;
            *(f32x4*)&agg[(size_t)node * C_IN + cb + 4] = t1;
        }
    }
}

// =============== GEMM (scalar, layer 2): g2h = fp16(dis*relu(agg @ W + B)). ======
template <int C_IN, int C_OUT, bool OUT_HALF>
__global__ __launch_bounds__(256, 3)
void gemm_kernel(const float* __restrict__ agg, const float* __restrict__ W,
                 const float* __restrict__ Bias, const float* __restrict__ dis,
                 void* __restrict__ g_out_v, int n) {
    constexpr int QW = C_OUT / 16;
    constexpr int RPT = QW;
    constexpr int LOGQ = (QW == 8) ? 3 : (QW == 4) ? 2 : 1;
    constexpr int CH = C_IN / 4;
    constexpr int SA = 68;

    constexpr int W_BYTES = C_IN * C_OUT * 4 + C_OUT * 4;
    constexpr int R1 = (W_BYTES + 15) & ~15;
    constexpr int AT_BYTES = C_IN * SA * 4;
    __shared__ char smem[R1 + AT_BYTES];
    __shared__ float sDis[64];

    float* sW = (float*)smem;
    float* sB = sW + C_IN * C_OUT;
    float* sAt = (float*)(smem + R1);

    const int tid = threadIdx.x;
    const int base = blockIdx.x * 64;

    for (int i = tid; i < C_IN * C_OUT / 4; i += 256)
        ((f32x4*)sW)[i] = ((const f32x4*)W)[i];
    if (tid < C_OUT) sB[tid] = Bias[tid];
    {
        constexpr int RPP = 256 / CH;
        const int r = tid / CH, c0 = tid % CH;
        #pragma unroll
        for (int p = 0; p < 64 / RPP; ++p) {
            const int rr = p * RPP + r;
            const int node = base + rr;
            f32x4 v = {0.f, 0.f, 0.f, 0.f};
            if (node < n) v = *(const f32x4*)&agg[(size_t)node * C_IN + c0 * 4];
            sAt[(c0 * 4 + 0) * SA + rr] = v.x;
            sAt[(c0 * 4 + 1) * SA + rr] = v.y;
            sAt[(c0 * 4 + 2) * SA + rr] = v.z;
            sAt[(c0 * 4 + 3) * SA + rr] = v.w;
        }
    }
    if (tid < 64) sDis[tid] = (base + tid < n) ? dis[base + tid] : 0.f;
    __syncthreads();

    const int w = tid >> 6, l = tid & 63;
    const int j = l & (QW - 1);
    const int rg = l >> LOGQ;
    const int ob = w * (C_OUT / 4) + j * 4;

    f32x4 acc[RPT];
    {
        const f32x4 bv = *(const f32x4*)&sB[ob];
        #pragma unroll
        for (int r = 0; r < RPT; ++r) acc[r] = bv;
    }

    #pragma unroll 4
    for (int k = 0; k < C_IN; ++k) {
        const f32x4 wv = ((const f32x4*)sW)[k * (C_OUT / 4) + (ob >> 2)];
        float av[RPT];
        if constexpr (RPT == 4) {
            const f32x4 a0 = *(const f32x4*)&sAt[k * SA + rg * 4];
            av[0] = a0.x; av[1] = a0.y; av[2] = a0.z; av[3] = a0.w;
        } else {
            const float2 a0 = *(const float2*)&sAt[k * SA + rg * 2];
            av[0] = a0.x; av[1] = a0.y;
        }
        #pragma unroll
        for (int r = 0; r < RPT; ++r) {
            acc[r].x = fmaf(av[r], wv.x, acc[r].x);
            acc[r].y = fmaf(av[r], wv.y, acc[r].y);
            acc[r].z = fmaf(av[r], wv.z, acc[r].z);
            acc[r].w = fmaf(av[r], wv.w, acc[r].w);
        }
    }

    #pragma unroll
    for (int r = 0; r < RPT; ++r) {
        const int row = rg * RPT + r;
        const int node = base + row;
        if (node < n) {
            const float sd = sDis[row];
            const float o0 = sd * fmaxf(acc[r].x, 0.f);
            const float o1 = sd * fmaxf(acc[r].y, 0.f);
            const float o2 = sd * fmaxf(acc[r].z, 0.f);
            const float o3 = sd * fmaxf(acc[r].w, 0.f);
            if constexpr (OUT_HALF) {
                __half2 lo = __floats2half2_rn(o0, o1);
                __half2 hi = __floats2half2_rn(o2, o3);
                uint2 pk;
                pk.x = *(unsigned int*)&lo;
                pk.y = *(unsigned int*)&hi;
                *(uint2*)((__half*)g_out_v + (size_t)node * C_OUT + ob) = pk;
            } else {
                f32x4 o; o.x = o0; o.y = o1; o.z = o2; o.w = o3;
                *(f32x4*)((float*)g_out_v + (size_t)node * C_OUT + ob) = o;
            }
        }
    }
}

// =============== FUSED layer 3: agg(C32) -> LDS -> GEMM(32->64) -> g3h fp16. =====
// Agg phase: 64 groups of 4 lanes own the block's 64 rows exactly; results go
// straight to sAt (transposed) — no aggb roundtrip, no extra dispatch.
__global__ __launch_bounds__(256, 6)
void fused_layer3(const __half* __restrict__ g2h, const int2* __restrict__ meta,
                  const int* __restrict__ csr_src, const float* __restrict__ dis,
                  const float* __restrict__ W, const float* __restrict__ Bias,
                  __half* __restrict__ g3h, int n) {
    constexpr int SA = 68;
    __shared__ float sW[32 * 64];      // 8 KB
    __shared__ float sB[64];
    __shared__ float sAt[32 * SA];     // 8.7 KB
    __shared__ float sDis[64];

    const int tid = threadIdx.x;
    const int base = blockIdx.x * 64;
    const int lane = tid & 63, wv = tid >> 6;

    for (int i = tid; i < 32 * 64 / 4; i += 256)
        ((f32x4*)sW)[i] = ((const f32x4*)W)[i];
    if (tid < 64) sB[tid] = Bias[tid];
    if (tid < 64) sDis[tid] = (base + tid < n) ? dis[base + tid] : 0.f;

    // ---- agg phase: group = 4 lanes, row = wv*16 + lane/4 ----
    {
        const int row = wv * 16 + (lane >> 2);
        const int sl = lane & 3;
        const int cb = sl * 8;
        const int node = base + row;
        const bool valid = node < n;
        const int2 mt = valid ? meta[node] : make_int2(0, 0);
        const int start = mt.x, m = mt.y;

        float a[8];
        #pragma unroll
        for (int q = 0; q < 8; ++q) a[q] = 0.f;

        for (int j = 0; j < m; j += 8) {
            int ss[8]; float mm[8];
            #pragma unroll
            for (int u = 0; u < 8; ++u) {
                const int jj = j + u;
                const bool ok = jj < m;
                ss[u] = csr_src[start + (ok ? jj : 0)];
                mm[u] = ok ? 1.f : 0.f;
            }
            i32x4 hr[8];
            const __half* ap[8];
            #pragma unroll
            for (int u = 0; u < 8; ++u) ap[u] = g2h + (size_t)ss[u] * 32 + cb;
            #pragma unroll
            for (int u = 0; u < 8; ++u)
                asm volatile("global_load_dwordx4 %0, %1, off"
                             : "=v"(hr[u]) : "v"(ap[u]) : "memory");
            asm volatile("s_waitcnt vmcnt(0)" ::: "memory");
            __builtin_amdgcn_sched_barrier(0);         // rule #18
            #pragma unroll
            for (int u = 0; u < 8; ++u) {
                #pragma unroll
                for (int q = 0; q < 4; ++q) {
                    const int wbits = hr[u][q];
                    const __half2 h2 = *(const __half2*)&wbits;
                    const float2 f2 = __half22float2(h2);
                    a[2 * q]     = fmaf(mm[u], f2.x, a[2 * q]);
                    a[2 * q + 1] = fmaf(mm[u], f2.y, a[2 * q + 1]);
                }
            }
        }
        float d0 = 0.f;
        if (valid) {
            d0 = dis[node];
            const __half* hp = g2h + (size_t)node * 32 + cb;
            #pragma unroll
            for (int q = 0; q < 4; ++q) {
                const __half2 h2 = *(const __half2*)(hp + 2 * q);
                const float2 f2 = __half22float2(h2);
                a[2 * q]     = (a[2 * q]     + f2.x) * d0;
                a[2 * q + 1] = (a[2 * q + 1] + f2.y) * d0;
            }
        }
        #pragma unroll
        for (int q = 0; q < 8; ++q)
            sAt[(cb + q) * SA + row] = valid ? a[q] : 0.f;
    }
    __syncthreads();

    // ---- gemm phase: QW=4, RPT=4 ----
    const int j = lane & 3;
    const int rg = lane >> 2;
    const int ob = wv * 16 + j * 4;

    f32x4 acc[4];
    {
        const f32x4 bv = *(const f32x4*)&sB[ob];
        #pragma unroll
        for (int r = 0; r < 4; ++r) acc[r] = bv;
    }
    #pragma unroll 4
    for (int k = 0; k < 32; ++k) {
        const f32x4 wvv = ((const f32x4*)sW)[k * 16 + (ob >> 2)];
        const f32x4 a0 = *(const f32x4*)&sAt[k * SA + rg * 4];
        float av[4] = {a0.x, a0.y, a0.z, a0.w};
        #pragma unroll
        for (int r = 0; r < 4; ++r) {
            acc[r].x = fmaf(av[r], wvv.x, acc[r].x);
            acc[r].y = fmaf(av[r], wvv.y, acc[r].y);
            acc[r].z = fmaf(av[r], wvv.z, acc[r].z);
            acc[r].w = fmaf(av[r], wvv.w, acc[r].w);
        }
    }
    #pragma unroll
    for (int r = 0; r < 4; ++r) {
        const int row = rg * 4 + r;
        const int node = base + row;
        if (node < n) {
            const float sd = sDis[row];
            __half2 lo = __floats2half2_rn(sd * fmaxf(acc[r].x, 0.f), sd * fmaxf(acc[r].y, 0.f));
            __half2 hi = __floats2half2_rn(sd * fmaxf(acc[r].z, 0.f), sd * fmaxf(acc[r].w, 0.f));
            uint2 pk;
            pk.x = *(unsigned int*)&lo;
            pk.y = *(unsigned int*)&hi;
            *(uint2*)((__half*)g3h + (size_t)node * 64 + ob) = pk;
        }
    }
}

// =============== FUSED layer 4: agg(C64) -> LDS -> MFMA(64->128) -> pool. ========
// sP overlays sAt (phases barrier-separated). A-fragment from sAt with fp16 cvt.
__global__ __launch_bounds__(256, 4)
void fused_layer4(const __half* __restrict__ g3h, const int2* __restrict__ meta,
                  const int* __restrict__ csr_src, const float* __restrict__ dis,
                  const _Float16* __restrict__ Wpk, const float* __restrict__ Bias,
                  const int* __restrict__ batchv, float* __restrict__ pooled, int n) {
    constexpr int SA = 68;
    constexpr int AT_BYTES = 64 * SA * 4;              // 17.4 KB
    constexpr int P_BYTES = 4 * 16 * 132 * 4;          // 33.8 KB
    __shared__ char smem[(AT_BYTES > P_BYTES ? AT_BYTES : P_BYTES)];
    __shared__ int sGb[64];
    float* sAt = (float*)smem;
    float* sP = (float*)smem;                          // [4][16][132] overlay

    const int tid = threadIdx.x;
    const int lane = tid & 63, wv = tid >> 6;
    const int base = blockIdx.x * 64;

    if (tid < 64) sGb[tid] = (base + tid < n) ? batchv[base + tid] : -1;

    // ---- agg phase: group = 8 lanes; rows grp and grp+32 ----
    {
        const int grp = wv * 8 + (lane >> 3);
        const int sl = lane & 7;
        const int cb = sl * 8;
        #pragma unroll 1
        for (int rr = 0; rr < 2; ++rr) {
            const int row = grp + rr * 32;
            const int node = base + row;
            const bool valid = node < n;
            const int2 mt = valid ? meta[node] : make_int2(0, 0);
            const int start = mt.x, m = mt.y;

            float a[8];
            #pragma unroll
            for (int q = 0; q < 8; ++q) a[q] = 0.f;

            for (int j = 0; j < m; j += 8) {
                int ss[8]; float mm[8];
                #pragma unroll
                for (int u = 0; u < 8; ++u) {
                    const int jj = j + u;
                    const bool ok = jj < m;
                    ss[u] = csr_src[start + (ok ? jj : 0)];
                    mm[u] = ok ? 1.f : 0.f;
                }
                i32x4 hr[8];
                const __half* ap[8];
                #pragma unroll
                for (int u = 0; u < 8; ++u) ap[u] = g3h + (size_t)ss[u] * 64 + cb;
                #pragma unroll
                for (int u = 0; u < 8; ++u)
                    asm volatile("global_load_dwordx4 %0, %1, off"
                                 : "=v"(hr[u]) : "v"(ap[u]) : "memory");
                asm volatile("s_waitcnt vmcnt(0)" ::: "memory");
                __builtin_amdgcn_sched_barrier(0);     // rule #18
                #pragma unroll
                for (int u = 0; u < 8; ++u) {
                    #pragma unroll
                    for (int q = 0; q < 4; ++q) {
                        const int wbits = hr[u][q];
                        const __half2 h2 = *(const __half2*)&wbits;
                        const float2 f2 = __half22float2(h2);
                        a[2 * q]     = fmaf(mm[u], f2.x, a[2 * q]);
                        a[2 * q + 1] = fmaf(mm[u], f2.y, a[2 * q + 1]);
                    }
                }
            }
            float d0 = 0.f;
            if (valid) {
                d0 = dis[node];
                const __half* hp = g3h + (size_t)node * 64 + cb;
                #pragma unroll
                for (int q = 0; q < 4; ++q) {
                    const __half2 h2 = *(const __half2*)(hp + 2 * q);
                    const float2 f2 = __half22float2(h2);
                    a[2 * q]     = (a[2 * q]     + f2.x) * d0;
                    a[2 * q + 1] = (a[2 * q + 1] + f2.y) * d0;
                }
            }
            #pragma unroll
            for (int q = 0; q < 8; ++q)
                sAt[(cb + q) * SA + row] = valid ? a[q] : 0.f;
        }
    }
    __syncthreads();

    // ---- A-fragment load from sAt (fp16 cvt); banks (4k+row)%32, conflict-free --
    const int row_a = wv * 16 + (lane & 15);
    const int kb = lane >> 4;
    f16x8 a0, a1;
    #pragma unroll
    for (int i = 0; i < 8; ++i) {
        const int k0 = 4 * kb + (i & 3) + 16 * (i >> 2);       // kk=0
        const int k1 = 32 + k0;                                 // kk=1
        a0[i] = (_Float16)sAt[k0 * SA + row_a];
        a1[i] = (_Float16)sAt[k1 * SA + row_a];
    }
    __syncthreads();   // all sAt reads complete before sP overlay writes

    f32x4 acc[8];
    #pragma unroll
    for (int ct = 0; ct < 8; ++ct) {
        f32x4 z = {0.f, 0.f, 0.f, 0.f};
        const f16x8 b0 = *(const f16x8*)(Wpk + ((ct * 2 + 0) * 64 + lane) * 8);
        const f16x8 b1 = *(const f16x8*)(Wpk + ((ct * 2 + 1) * 64 + lane) * 8);
        z = __builtin_amdgcn_mfma_f32_16x16x32_f16(a0, b0, z, 0, 0, 0);
        z = __builtin_amdgcn_mfma_f32_16x16x32_f16(a1, b1, z, 0, 0, 0);
        acc[ct] = z;
    }

    #pragma unroll
    for (int ct = 0; ct < 8; ++ct) {
        const float b = Bias[ct * 16 + (lane & 15)];
        #pragma unroll
        for (int r = 0; r < 4; ++r) {
            const int mrow = (lane >> 4) * 4 + r;
            sP[(wv * 16 + mrow) * 132 + ct * 16 + (lane & 15)] = fmaxf(acc[ct][r] + b, 0.f);
        }
    }
    __syncthreads();

    if (tid < 128) {
        const int c = tid;
        int curg = -1; float run = 0.f;
        for (int r2 = 0; r2 < 64; ++r2) {
            const int gb = sGb[r2];
            if (gb < 0) continue;
            const float v = sP[r2 * 132 + c];
            if (gb != curg) {
                if (curg >= 0)
                    atomicMax((int*)&pooled[(size_t)curg * 128 + c], __float_as_int(run));
                curg = gb; run = v;
            } else {
                run = fmaxf(run, v);
            }
        }
        if (curg >= 0)
            atomicMax((int*)&pooled[(size_t)curg * 128 + c], __float_as_int(run));
    }
}

// ---------------- MLP head: relu(pooled @ W5 + b5) @ W6 + b6 ----------------
__global__ void mlp_kernel(const float* __restrict__ pooled,
                           const float* __restrict__ W5, const float* __restrict__ b5,
                           const float* __restrict__ W6, const float* __restrict__ b6,
                           float* __restrict__ out) {
    const int g = blockIdx.x;
    const int t = threadIdx.x;  // 64 threads
    __shared__ float row[128];
    __shared__ float hid[64];
    row[t] = pooled[g * 128 + t];
    row[64 + t] = pooled[g * 128 + 64 + t];
    __syncthreads();
    float v = b5[t];
    #pragma unroll 8
    for (int c = 0; c < 128; ++c) v = fmaf(row[c], W5[c * 64 + t], v);
    hid[t] = fmaxf(v, 0.f);
    __syncthreads();
    if (t < 10) {
        float o = b6[t];
        #pragma unroll 8
        for (int c = 0; c < 64; ++c) o = fmaf(hid[c], W6[c * 10 + t], o);
        out[g * 10 + t] = o;
    }
}

extern "C" void kernel_launch(void* const* d_in, const int* in_sizes, int n_in,
                              void* d_out, int out_size, void* d_ws, size_t ws_size,
                              hipStream_t stream) {
    const float* x     = (const float*)d_in[0];
    const int*   ei    = (const int*)d_in[1];
    const int*   batch = (const int*)d_in[2];
    const float* W1 = (const float*)d_in[3];  const float* b1 = (const float*)d_in[4];
    const float* W2 = (const float*)d_in[5];  const float* b2 = (const float*)d_in[6];
    const float* W3 = (const float*)d_in[7];  const float* b3 = (const float*)d_in[8];
    const float* W4 = (const float*)d_in[9];  const float* b4 = (const float*)d_in[10];
    const float* W5 = (const float*)d_in[11]; const float* b5 = (const float*)d_in[12];
    const float* W6 = (const float*)d_in[13]; const float* b6 = (const float*)d_in[14];
    float* out = (float*)d_out;

    const int N = in_sizes[0] / 2;       // 100000
    const int E = in_sizes[1] / 2;       // 1600000
    const int G = out_size / 10;         // 512

    // workspace layout
    char* p = (char*)d_ws;
    auto take = [&](size_t bytes) -> void* {
        void* r = (void*)p;
        p += (bytes + 255) & ~(size_t)255;
        return r;
    };
    int*       bktCur = (int*)take(NBKT * 4);
    int*       arena  = (int*)take((size_t)NBKT * BCAP * 4);
    int*       csr_src= (int*)take((size_t)NBKT * BCAP * 4);
    float*     dis    = (float*)take((size_t)N * 4);
    int2*      meta   = (int2*)take((size_t)N * 8);
    float*     g0     = (float*)take((size_t)N * 2 * 4);
    __half*    g1h    = (__half*)take((size_t)N * 16 * 2);
    __half*    g2h    = (__half*)take((size_t)N * 32 * 2);
    __half*    g3h    = (__half*)take((size_t)N * 64 * 2);
    float*     aggb   = (float*)take((size_t)N * 16 * 4);
    _Float16*  Wpk    = (_Float16*)take(8192 * 2);
    float*     pooled = (float*)take((size_t)G * 128 * 4);

    init_kernel<<<(512 * 128 + 255) / 256, 256, 0, stream>>>(bktCur, pooled, W4, Wpk);

    const int PBLK = (E + EPB - 1) / EPB;    // 391
    partition_kernel<<<PBLK, 256, 0, stream>>>(ei, E, bktCur, arena);
    bucket_csr_kernel<<<NBKT, 512, 0, stream>>>(arena, bktCur, csr_src, meta, dis, x, g0, N);

    gcn_l1_lane<<<(N + 255) / 256, 256, 0, stream>>>(g0, meta, csr_src, dis, W1, b1, g1h, N);

    const int GBLK = (N + 63) / 64;

    agg_group_kernel<16, false><<<(N + 127) / 128, 256, 0, stream>>>(g1h, meta, csr_src, dis, aggb, N);
    gemm_kernel<16, 32, true><<<GBLK, 256, 0, stream>>>(aggb, W2, b2, dis, g2h, N);

    fused_layer3<<<GBLK, 256, 0, stream>>>(g2h, meta, csr_src, dis, W3, b3, g3h, N);
    fused_layer4<<<GBLK, 256, 0, stream>>>(g3h, meta, csr_src, dis, Wpk, b4, batch, pooled, N);

    mlp_kernel<<<G, 64, 0, stream>>>(pooled, W5, b5, W6, b6, out);
}